// Round 11
// baseline (80.951 us; speedup 1.0000x reference)
//
#include <hip/hip_runtime.h>
#include <hip/hip_bf16.h>
#include <math.h>

// SlowROIPool: adaptive 7x7 max-pool over integer ROI crops.
// images [N=4,C=256,H=50,W=50] f32, rois [R=256,4] f32, roi_idx [R] i32.
// out [R,C,7,7] f32.
//
// R10 lesson: DS-op cuts bought little -> main kernel is VALU/redundancy
// bound: 32768 waves each re-derived per-ROI box/bin math (256 distinct).
// R11: hoist it.
//  K1 (prep): per ROI write packed params {n,y1,x1,sh,sw} and per (ROI,lane)
//     tap descriptor {vb, dh, dw} into d_ws (R10's math verbatim).
//  K2 (pool): R10's verified staging/LDS/compute, but setup = 1 scalar load
//     + 1 coalesced load + unpack; staging unroll class-branched on sh
//     (5/8/11 rounds) to skip never-read rows (reads past staged rows are
//     mask-discarded, so this is correctness-neutral).
// All unpacked values are re-clamped in K2: even a corrupted table cannot
// produce an out-of-bounds global or LDS address.

#define S 7
#define NN 4
#define NC 256
#define NH 50
#define NW 50
#define PLANE (NH * NW)   // 2500
#define MAXD 22           // max crop dim (bw,bh <= 0.4 -> span <= 22)
#define PITCH 33          // > 31 required by 2x32 staging layout (R9 bug)
#define PPW 2             // planes (channels) per wave
#define WPB 4             // waves per block
#define NINF (-__builtin_huge_valf())

// ---------------- K1: per-ROI precompute ----------------
__global__ __launch_bounds__(256) void prep_kernel(
    const float* __restrict__ rois,
    const int* __restrict__ roi_idx,
    unsigned* __restrict__ params,   // [256]
    unsigned* __restrict__ taps)     // [256*64]
{
    const int tid  = blockIdx.x * 256 + threadIdx.x;   // 64 blocks -> 16384
    const int r    = tid >> 6;                         // 0..255
    const int lane = tid & 63;

    const float rx1 = rois[4 * r + 0];
    const float ry1 = rois[4 * r + 1];
    const float rx2 = rois[4 * r + 2];
    const float ry2 = rois[4 * r + 3];
    int x1 = (int)floorf(rx1 * (float)NW);
    int y1 = (int)floorf(ry1 * (float)NH);
    int x2 = (int)ceilf(rx2 * (float)NW);
    int y2 = (int)ceilf(ry2 * (float)NH);
    x1 = min(max(x1, 0), NW - 1);
    y1 = min(max(y1, 0), NH - 1);
    x2 = min(max(x2, x1 + 1), NW);
    y2 = min(max(y2, y1 + 1), NH);
    const int sw = min(x2 - x1, MAXD);   // identity on real data
    const int sh = min(y2 - y1, MAXD);

    const int l  = min(lane, S * S - 1);
    const int i  = l / S;
    const int j  = l - i * S;
    const int hs = (i * sh) / S;
    const int he = ((i + 1) * sh + S - 1) / S;
    const int ws_ = (j * sw) / S;
    const int we_ = ((j + 1) * sw + S - 1) / S;
    const int dh = he - hs;                 // [1,4]
    const int dw = we_ - ws_;               // [1,4]
    const int vb = hs * PITCH + ws_;        // <= 612

    taps[tid] = (unsigned)vb | ((unsigned)dh << 10) | ((unsigned)dw << 13);

    if (lane == 0) {
        int n = roi_idx[r];
        n = min(max(n, 0), NN - 1);
        params[r] = (unsigned)n | ((unsigned)y1 << 2) | ((unsigned)x1 << 8)
                  | ((unsigned)sh << 14) | ((unsigned)sw << 19);
    }
}

// ---------------- K2 staging helper: Q fixed rounds, 2 planes ----------------
template <int Q>
__device__ __forceinline__ void stage_pair(
    const float* __restrict__ gb, float* __restrict__ L0,
    float* __restrict__ L1, int sh, int rh, int wb)
{
    float v0[Q], v1[Q];
#pragma unroll
    for (int q = 0; q < Q; ++q) {
        const int hc = min(2 * q + rh, sh - 1);   // rows >= sh: dup, never read
        v0[q] = gb[hc * NW];
        v1[q] = gb[PLANE + hc * NW];              // 2Q batched independent loads
    }
#pragma unroll
    for (int q = 0; q < Q; ++q) L0[wb + q * 2 * PITCH] = v0[q];
#pragma unroll
    for (int q = 0; q < Q; ++q) L1[wb + q * 2 * PITCH] = v1[q];
}

// ---------------- K2: pool ----------------
__global__ __launch_bounds__(256) void roipool_kernel(
    const float* __restrict__ images,
    const unsigned* __restrict__ params,
    const unsigned* __restrict__ taps,
    float* __restrict__ out,
    int out_size)
{
    __shared__ float lds[WPB][PPW][MAXD * PITCH];   // 23.2 KB

    const int t    = threadIdx.x;
    const int wid  = t >> 6;
    const int lane = t & 63;
    const int pair = blockIdx.x * WPB + wid;
    int r = __builtin_amdgcn_readfirstlane(pair >> 7);   // 128 pairs per ROI
    r = min(max(r, 0), 255);
    const int c0 = (pair & 127) * PPW;

    // scalar param load (r uniform) + clamped unpack
    const unsigned pk = params[r];
    const int n  = pk & 3;
    int y1 = (pk >> 2) & 63;  y1 = min(y1, NH - 1);
    int x1 = (pk >> 8) & 63;  x1 = min(x1, NW - 1);
    int sh = (pk >> 14) & 31; sh = min(min(max(sh, 1), NH - y1), MAXD);
    int sw = (pk >> 19) & 31; sw = min(min(max(sw, 1), NW - x1), MAXD);

    // per-lane tap descriptor (coalesced load) + clamped unpack
    const unsigned tp = taps[r * 64 + lane];
    int vb = (int)(tp & 1023); vb = min(vb, 612);   // +102 <= 714 < 726
    const int dh = (tp >> 10) & 7;
    const int dw = (tp >> 13) & 7;

    // ---- staging: class-branched fixed rounds (sh scalar -> uniform) ----
    const int wl  = lane & 31;
    const int rh  = lane >> 5;
    const int wlc = min(wl, sw - 1);
    const float* __restrict__ gb =
        images + (size_t)(n * NC + c0) * PLANE + (y1 * NW + x1) + wlc;
    float* __restrict__ L0 = &lds[wid][0][0];
    float* __restrict__ L1 = &lds[wid][1][0];
    const int wb = rh * PITCH + wl;

    if (sh <= 10)      stage_pair<5>(gb, L0, L1, sh, rh, wb);
    else if (sh <= 16) stage_pair<8>(gb, L0, L1, sh, rh, wb);
    else               stage_pair<11>(gb, L0, L1, sh, rh, wb);

    // ---- compute: 16 const-delta taps, validity via cndmask ----
    float m0 = NINF, m1 = NINF;
#pragma unroll
    for (int a = 0; a < 4; ++a) {
#pragma unroll
        for (int b = 0; b < 4; ++b) {
            const bool valid = (a < dh) & (b < dw);
            const float x0 = L0[vb + a * PITCH + b];
            const float x1v = L1[vb + a * PITCH + b];
            m0 = fmaxf(m0, valid ? x0 : NINF);
            m1 = fmaxf(m1, valid ? x1v : NINF);
        }
    }

    // ---- stores: 49 contiguous floats per plane ----
    if (lane < S * S) {
        const size_t o0 = (size_t)(r * NC + c0) * (S * S) + lane;
        const size_t o1 = o0 + (S * S);
        if (o0 < (size_t)out_size) out[o0] = m0;
        if (o1 < (size_t)out_size) out[o1] = m1;
    }
}

extern "C" void kernel_launch(void* const* d_in, const int* in_sizes, int n_in,
                              void* d_out, int out_size, void* d_ws, size_t ws_size,
                              hipStream_t stream) {
    const float* images  = (const float*)d_in[0];
    const float* rois    = (const float*)d_in[1];
    const int*   roi_idx = (const int*)d_in[2];
    float* out = (float*)d_out;

    unsigned* params = (unsigned*)d_ws;        // 256 u32
    unsigned* taps   = params + 256;           // 16384 u32 (66.5 KB total)

    prep_kernel<<<64, 256, 0, stream>>>(rois, roi_idx, params, taps);

    const int planes = out_size / (S * S);           // 65536
    const int pairs  = (planes + PPW - 1) / PPW;     // 32768
    const int blocks = (pairs + WPB - 1) / WPB;      // 8192
    roipool_kernel<<<blocks, 256, 0, stream>>>(images, params, taps, out, out_size);
}

// Round 12
// 77.662 us; speedup vs baseline: 1.0424x; 1.0424x over previous
//
#include <hip/hip_runtime.h>
#include <hip/hip_bf16.h>
#include <math.h>

// SlowROIPool: adaptive 7x7 max-pool over integer ROI crops.
// images [N=4,C=256,H=50,W=50] f32, rois [R=256,4] f32, roi_idx [R] i32.
// out [R,C,7,7] f32.
//
// R10/R11 lesson: DS-op and VALU cuts were ~neutral -> bottleneck is the
// per-wave staging-latency exposure (32768 short waves) + scalar-width moves.
// R12: 4 planes per wave (16384 waves, box math amortized 4x, ONE batched
// latency exposure for all 4 planes) + float2 staging:
//   lane = (r4: 4 rows) x (w2: 16 col-pairs) stages a FIXED 32-col window
//   from x1a = min(x1&~1, 18): even -> all global/LDS float2 accesses are
//   8B-aligned; [x1a, x1a+32) always inside the 50-col row, rows clamped to
//   sh-1 -> no address can leave the plane even under poisoned inputs.
//   Rounds class-branched on sh: Q = 3/5/6 (covers 12/20/24 rows).
// Compute = R10's verified path: unclamped const-delta taps off one vaddr,
// validity (a<dh)&(b<dw) via cndmask (over-reads land in the padded 24x34
// buffer and are always mask-discarded). 2 LDS plane-buffers per wave,
// single-buffered across the two pairs (same-wave DS ordering is in-order).

#define S 7
#define NN 4
#define NC 256
#define NH 50
#define NW 50
#define PLANE (NH * NW)   // 2500
#define PITCH 34          // even (float2 align); > 31
#define PROWS 24          // padded rows (max staged slot = 23)
#define PBUF (PROWS * PITCH)  // 816 floats per plane buffer
#define WPB 4             // waves per block
#define NINF (-__builtin_huge_valf())

__device__ __forceinline__ float tapmax(const float* __restrict__ L,
                                        int vb, int dh, int dw)
{
    float m = NINF;
#pragma unroll
    for (int a = 0; a < 4; ++a) {
#pragma unroll
        for (int b = 0; b < 4; ++b) {
            const bool valid = (a < dh) & (b < dw);
            const float x = L[vb + a * PITCH + b];   // const-delta, in padded buf
            m = fmaxf(m, valid ? x : NINF);
        }
    }
    return m;
}

template <int Q>
__device__ __forceinline__ void wave_body(
    const float* __restrict__ gb,    // plane0 base + y1*NW + x1a + 2*w2
    float* __restrict__ L0, float* __restrict__ L1,
    int sh, int r4, int vb, int dh, int dw, int slotbase,
    float m[4])
{
    float2 v[4][Q];
    // ---- all 4 planes' staging loads in ONE batch (single latency exposure)
#pragma unroll
    for (int p = 0; p < 4; ++p) {
#pragma unroll
        for (int q = 0; q < Q; ++q) {
            const int rc = min(q * 4 + r4, sh - 1);  // dup rows: masked later
            v[p][q] = *(const float2*)(gb + (size_t)p * PLANE + rc * NW);
        }
    }
    // ---- pair 0: write planes 0,1 -> L0,L1; compute ----
#pragma unroll
    for (int q = 0; q < Q; ++q) {
        const int slot = slotbase + q * 4 * PITCH;   // 8B-aligned (even)
        *(float2*)(L0 + slot) = v[0][q];
        *(float2*)(L1 + slot) = v[1][q];
    }
    m[0] = tapmax(L0, vb, dh, dw);
    m[1] = tapmax(L1, vb, dh, dw);
    // ---- pair 1: same buffers (same-wave DS ops are in-order: safe) ----
#pragma unroll
    for (int q = 0; q < Q; ++q) {
        const int slot = slotbase + q * 4 * PITCH;
        *(float2*)(L0 + slot) = v[2][q];
        *(float2*)(L1 + slot) = v[3][q];
    }
    m[2] = tapmax(L0, vb, dh, dw);
    m[3] = tapmax(L1, vb, dh, dw);
}

__global__ __launch_bounds__(256, 4) void roipool_kernel(
    const float* __restrict__ images,
    const float* __restrict__ rois,
    const int* __restrict__ roi_idx,
    float* __restrict__ out,
    int out_size)
{
    __shared__ float lds[WPB][2][PBUF];   // 4*2*816*4 = 26.1 KB

    const int t    = threadIdx.x;
    const int wid  = __builtin_amdgcn_readfirstlane(t >> 6);
    const int lane = t & 63;
    const int grp  = blockIdx.x * WPB + wid;   // 4-plane group, < 16384
    int r = __builtin_amdgcn_readfirstlane(grp >> 6);   // 64 groups per ROI
    r = min(max(r, 0), 255);
    const int c0 = (grp & 63) * 4;

    // ---- box math: scalar, clamped (identity on sane inputs) ----
    const float rx1 = rois[4 * r + 0];
    const float ry1 = rois[4 * r + 1];
    const float rx2 = rois[4 * r + 2];
    const float ry2 = rois[4 * r + 3];
    int x1 = __builtin_amdgcn_readfirstlane((int)floorf(rx1 * (float)NW));
    int y1 = __builtin_amdgcn_readfirstlane((int)floorf(ry1 * (float)NH));
    int x2 = __builtin_amdgcn_readfirstlane((int)ceilf(rx2 * (float)NW));
    int y2 = __builtin_amdgcn_readfirstlane((int)ceilf(ry2 * (float)NH));
    x1 = min(max(x1, 0), NW - 1);
    y1 = min(max(y1, 0), NH - 1);
    x2 = min(max(x2, x1 + 1), NW);
    y2 = min(max(y2, y1 + 1), NH);
    const int sw = min(x2 - x1, 22);     // identity on real data (<= 22)
    const int sh = min(y2 - y1, 22);

    int n = __builtin_amdgcn_readfirstlane(roi_idx[r]);
    n = min(max(n, 0), NN - 1);

    // staged window start: even, window [x1a, x1a+32) always inside the row
    const int x1a   = min(x1 & ~1, NW - 32);   // 0..18, even
    const int shift = x1 - x1a;                // 0..31

    // ---- per-lane bin (lanes 49..63 clone lane 48) ----
    const int l  = min(lane, S * S - 1);
    const int i  = l / S;
    const int j  = l - i * S;
    const int hs = (i * sh) / S;
    const int he = ((i + 1) * sh + S - 1) / S;
    const int ws = (j * sw) / S;
    const int we = ((j + 1) * sw + S - 1) / S;
    const int dh = he - hs;                    // [1,4]
    const int dw = we - ws;
    const int vb = hs * PITCH + ws + shift;    // max read 745 < 816 (padded)

    // ---- staging lane roles: 4 rows x 16 float2 cols ----
    const int r4 = lane >> 4;                  // 0..3
    const int w2 = lane & 15;                  // 0..15
    const int slotbase = r4 * PITCH + 2 * w2;  // even -> 8B-aligned LDS
    const float* __restrict__ gb =
        images + (size_t)(n * NC + c0) * PLANE + y1 * NW + x1a + 2 * w2;
    float* __restrict__ L0 = &lds[wid][0][0];
    float* __restrict__ L1 = &lds[wid][1][0];

    float m[4];
    if (sh <= 12)      wave_body<3>(gb, L0, L1, sh, r4, vb, dh, dw, slotbase, m);
    else if (sh <= 20) wave_body<5>(gb, L0, L1, sh, r4, vb, dh, dw, slotbase, m);
    else               wave_body<6>(gb, L0, L1, sh, r4, vb, dh, dw, slotbase, m);

    // ---- stores: 196 contiguous floats per wave ----
    if (lane < S * S) {
#pragma unroll
        for (int p = 0; p < 4; ++p) {
            const size_t oi = (size_t)(r * NC + c0 + p) * (S * S) + lane;
            if (oi < (size_t)out_size) out[oi] = m[p];
        }
    }
}

extern "C" void kernel_launch(void* const* d_in, const int* in_sizes, int n_in,
                              void* d_out, int out_size, void* d_ws, size_t ws_size,
                              hipStream_t stream) {
    const float* images  = (const float*)d_in[0];
    const float* rois    = (const float*)d_in[1];
    const int*   roi_idx = (const int*)d_in[2];
    float* out = (float*)d_out;

    const int planes = out_size / (S * S);      // 65536
    const int groups = (planes + 3) / 4;        // 16384
    const int blocks = (groups + WPB - 1) / WPB;  // 4096
    roipool_kernel<<<blocks, 256, 0, stream>>>(images, rois, roi_idx, out, out_size);
}

// Round 13
// 75.987 us; speedup vs baseline: 1.0653x; 1.0220x over previous
//
#include <hip/hip_runtime.h>
#include <hip/hip_bf16.h>
#include <math.h>

// SlowROIPool: adaptive 7x7 max-pool over integer ROI crops.
// images [N=4,C=256,H=50,W=50] f32, rois [R=256,4] f32, roi_idx [R] i32.
// out [R,C,7,7] f32.
//
// R12 lesson: kernel is DS-DATA-bound (~16 us of LDS bank cycles/CU: fixed
// 32-col staging stages ~2x the needed bytes; fixed 4x4 taps read ~4x the
// avg needed). LDS cost is data-limited (128 B/cyc), so cut BYTES:
//  - staging exec-masked to w2 < wpc=(shift+sw+1)/2 pairs (masked lanes move
//    no LDS data, skip their global loads),
//  - tap loop templated on wave-uniform max-spans A=SP(sh), B=SP(sw),
//    SP(s)= 2(s<=7)/3(s<=14)/4(else) — exhaustively verified for s=5..22,
//  - tap phase masked to lanes<49 (no clone-lane DS traffic).
// Structure else = R12 (verified): 4 planes/wave, float2 staging from even
// x1a with [x1a,x1a+32) always in-row, unclamped const-delta taps + cndmask,
// single-buffered pairs (same-wave DS ops are in-order).
// Coverage proof: used tap cols <= shift+sw-1 <= 2*wpc-1; discarded taps may
// hit unwritten LDS cells but stay inside the padded 816-float buffer.
// All indices clamped: no global/LDS access can leave its buffer even under
// transiently-poisoned inputs.

#define S 7
#define NN 4
#define NC 256
#define NH 50
#define NW 50
#define PLANE (NH * NW)   // 2500
#define PITCH 34          // even (float2 align); > 31
#define PROWS 24          // padded rows
#define PBUF (PROWS * PITCH)  // 816 floats per plane buffer
#define WPB 4             // waves per block
#define NINF (-__builtin_huge_valf())

template <int A, int B>
__device__ __forceinline__ float tapmax(const float* __restrict__ L,
                                        int vb, int dh, int dw)
{
    float m = NINF;
#pragma unroll
    for (int a = 0; a < A; ++a) {
#pragma unroll
        for (int b = 0; b < B; ++b) {
            const bool valid = (a < dh) & (b < dw);   // dh<=A, dw<=B by class
            const float x = L[vb + a * PITCH + b];    // in padded buffer
            m = fmaxf(m, valid ? x : NINF);
        }
    }
    return m;
}

template <int Q, int A, int B>
__device__ __forceinline__ void wave_body(
    const float* __restrict__ gb,    // plane0 base + y1*NW + x1a + 2*w2
    float* __restrict__ L0, float* __restrict__ L1,
    int sh, int r4, int vb, int dh, int dw, int slotbase,
    bool stager, bool computer, float m[4])
{
    float2 v[4][Q];
    if (stager) {                    // w2 < wpc: only useful bytes move
#pragma unroll
        for (int p = 0; p < 4; ++p) {
#pragma unroll
            for (int q = 0; q < Q; ++q) {
                const int rc = min(q * 4 + r4, sh - 1);   // dup rows: masked later
                v[p][q] = *(const float2*)(gb + (size_t)p * PLANE + rc * NW);
            }
        }
#pragma unroll
        for (int q = 0; q < Q; ++q) {
            const int slot = slotbase + q * 4 * PITCH;    // 8B-aligned
            *(float2*)(L0 + slot) = v[0][q];
            *(float2*)(L1 + slot) = v[1][q];
        }
    }
    if (computer) {
        m[0] = tapmax<A, B>(L0, vb, dh, dw);
        m[1] = tapmax<A, B>(L1, vb, dh, dw);
    }
    if (stager) {                    // same-wave DS in-order: WAR safe
#pragma unroll
        for (int q = 0; q < Q; ++q) {
            const int slot = slotbase + q * 4 * PITCH;
            *(float2*)(L0 + slot) = v[2][q];
            *(float2*)(L1 + slot) = v[3][q];
        }
    }
    if (computer) {
        m[2] = tapmax<A, B>(L0, vb, dh, dw);
        m[3] = tapmax<A, B>(L1, vb, dh, dw);
    }
}

__global__ __launch_bounds__(256, 4) void roipool_kernel(
    const float* __restrict__ images,
    const float* __restrict__ rois,
    const int* __restrict__ roi_idx,
    float* __restrict__ out,
    int out_size)
{
    __shared__ float lds[WPB][2][PBUF];   // 26.1 KB

    const int t    = threadIdx.x;
    const int wid  = __builtin_amdgcn_readfirstlane(t >> 6);
    const int lane = t & 63;
    const int grp  = blockIdx.x * WPB + wid;   // 4-plane group, < 16384
    int r = __builtin_amdgcn_readfirstlane(grp >> 6);   // 64 groups per ROI
    r = min(max(r, 0), 255);
    const int c0 = (grp & 63) * 4;

    // ---- box math: scalar, clamped (identity on sane inputs) ----
    const float rx1 = rois[4 * r + 0];
    const float ry1 = rois[4 * r + 1];
    const float rx2 = rois[4 * r + 2];
    const float ry2 = rois[4 * r + 3];
    int x1 = __builtin_amdgcn_readfirstlane((int)floorf(rx1 * (float)NW));
    int y1 = __builtin_amdgcn_readfirstlane((int)floorf(ry1 * (float)NH));
    int x2 = __builtin_amdgcn_readfirstlane((int)ceilf(rx2 * (float)NW));
    int y2 = __builtin_amdgcn_readfirstlane((int)ceilf(ry2 * (float)NH));
    x1 = min(max(x1, 0), NW - 1);
    y1 = min(max(y1, 0), NH - 1);
    x2 = min(max(x2, x1 + 1), NW);
    y2 = min(max(y2, y1 + 1), NH);
    const int sw = min(x2 - x1, 22);     // identity on real data (<= 22)
    const int sh = min(y2 - y1, 22);

    int n = __builtin_amdgcn_readfirstlane(roi_idx[r]);
    n = min(max(n, 0), NN - 1);

    // staged window: even start, [x1a, x1a+32) always inside the 50-col row
    const int x1a   = min(x1 & ~1, NW - 32);   // 0..18, even
    const int shift = x1 - x1a;                // 0..31; shift+sw <= 32

    // ---- per-lane bin (lanes 49..63 clone lane 48; masked in tap phase) ----
    const int l  = min(lane, S * S - 1);
    const int i  = l / S;
    const int j  = l - i * S;
    const int hs = (i * sh) / S;
    const int he = ((i + 1) * sh + S - 1) / S;
    const int ws = (j * sw) / S;
    const int we = ((j + 1) * sw + S - 1) / S;
    const int dh = he - hs;                    // <= SP(sh)
    const int dw = we - ws;                    // <= SP(sw)
    const int vb = hs * PITCH + ws + shift;    // max read 766 < 816 (padded)

    // ---- staging lane roles: 4 rows x 16 float2 cols, masked to wpc ----
    const int r4 = lane >> 4;                  // 0..3
    const int w2 = lane & 15;                  // 0..15
    const int wpc = (shift + sw + 1) >> 1;     // needed pairs, 1..16
    const bool stager   = (w2 < wpc);
    const bool computer = (lane < S * S);
    const int slotbase = r4 * PITCH + 2 * w2;
    const float* __restrict__ gb =
        images + (size_t)(n * NC + c0) * PLANE + y1 * NW + x1a + 2 * w2;
    float* __restrict__ L0 = &lds[wid][0][0];
    float* __restrict__ L1 = &lds[wid][1][0];

    float m[4] = {NINF, NINF, NINF, NINF};
    // sh class -> (Q rows-rounds, A); sw class -> B. Q*4 >= max sh of class.
    if (sh <= 7) {
        if (sw <= 7)       wave_body<2,2,2>(gb,L0,L1,sh,r4,vb,dh,dw,slotbase,stager,computer,m);
        else if (sw <= 14) wave_body<2,2,3>(gb,L0,L1,sh,r4,vb,dh,dw,slotbase,stager,computer,m);
        else               wave_body<2,2,4>(gb,L0,L1,sh,r4,vb,dh,dw,slotbase,stager,computer,m);
    } else if (sh <= 14) {
        if (sw <= 7)       wave_body<4,3,2>(gb,L0,L1,sh,r4,vb,dh,dw,slotbase,stager,computer,m);
        else if (sw <= 14) wave_body<4,3,3>(gb,L0,L1,sh,r4,vb,dh,dw,slotbase,stager,computer,m);
        else               wave_body<4,3,4>(gb,L0,L1,sh,r4,vb,dh,dw,slotbase,stager,computer,m);
    } else {
        if (sw <= 7)       wave_body<6,4,2>(gb,L0,L1,sh,r4,vb,dh,dw,slotbase,stager,computer,m);
        else if (sw <= 14) wave_body<6,4,3>(gb,L0,L1,sh,r4,vb,dh,dw,slotbase,stager,computer,m);
        else               wave_body<6,4,4>(gb,L0,L1,sh,r4,vb,dh,dw,slotbase,stager,computer,m);
    }

    // ---- stores: 196 contiguous floats per wave ----
    if (lane < S * S) {
#pragma unroll
        for (int p = 0; p < 4; ++p) {
            const size_t oi = (size_t)(r * NC + c0 + p) * (S * S) + lane;
            if (oi < (size_t)out_size) out[oi] = m[p];
        }
    }
}

extern "C" void kernel_launch(void* const* d_in, const int* in_sizes, int n_in,
                              void* d_out, int out_size, void* d_ws, size_t ws_size,
                              hipStream_t stream) {
    const float* images  = (const float*)d_in[0];
    const float* rois    = (const float*)d_in[1];
    const int*   roi_idx = (const int*)d_in[2];
    float* out = (float*)d_out;

    const int planes = out_size / (S * S);        // 65536
    const int groups = (planes + 3) / 4;          // 16384
    const int blocks = (groups + WPB - 1) / WPB;  // 4096
    roipool_kernel<<<blocks, 256, 0, stream>>>(images, rois, roi_idx, out, out_size);
}